// Round 5
// baseline (310.944 us; speedup 1.0000x reference)
//
#include <hip/hip_runtime.h>

// TokenMixer: out[n,b,c] = x_pos[n,b,c] * (1 - sigmoid(cos_sim(x_pre[n,b,:], x_pos[n,b,:])))
// N=4096, B=16, C=512 -> 65536 rows of 512 fp32.
//
// V5: stream time-skew. Post-mortem chain:
//   V1/V3/V4b (three schedules incl. FORCED 8KB/wave in flight) all ~110us,
//   2.4 TB/s -> bytes-in-flight is NOT the limiter; the memory system serves
//   this pattern at 2.4 TB/s. Hypothesis: pre/pos/out are 2^27 B apart ->
//   same-offset requests alias to the SAME HBM channel+bank (pow-2
//   interleave). Every wave reads pre[X] and pos[X] back-to-back -> per-wave
//   same-bank different-row ping-pong on one channel, chip-wide, every cycle.
//   A copy kernel (6.3 TB/s) has no such pairing.
//   Fix: 4-row/wave software pipeline where the pre stream runs 2 rows
//   (4 KB) AHEAD of the pos stream; stores trail by 1 row. Concurrent
//   traffic from one wave is then at different in-stream offsets ->
//   different channels. sched_barrier(0) fences pin the stage structure
//   (V3 lesson: the compiler re-fissions unfenced multi-row schedules).

typedef float f32x4 __attribute__((ext_vector_type(4)));

constexpr int C_DIM = 512;
constexpr int ROWS  = 4096 * 16;   // 65536

__device__ __forceinline__ f32x4 ld4(const float* p) {
    return *reinterpret_cast<const f32x4*>(p);
}

__global__ __launch_bounds__(256, 6) void tokenmixer_kernel(
    const float* __restrict__ pre,
    const float* __restrict__ pos,
    float* __restrict__ out)
{
    const int wave = (int)((blockIdx.x * 256u + threadIdx.x) >> 6);  // 0..16383
    const int lane = (int)(threadIdx.x & 63u);

    // 4 consecutive rows per wave
    const size_t base = (size_t)(4 * wave) * C_DIM + (size_t)(lane * 4);
    const float* pp = pre + base;
    const float* qq = pos + base;
    float*       oo = out + base;

    f32x4 pA0,pB0,pA1,pB1,pA2,pB2,pA3,pB3;
    f32x4 qA0,qB0,qA1,qB1,qA2,qB2,qA3,qB3;

    // ---- stage 0: pre rows 0,1 ; pos row 0  (pre leads pos by 1..2 rows) ----
    pA0 = ld4(pp);        pB0 = ld4(pp + 256);
    pA1 = ld4(pp + 512);  pB1 = ld4(pp + 768);
    qA0 = ld4(qq);        qB0 = ld4(qq + 256);
    __builtin_amdgcn_sched_barrier(0);

    // ---- stage 1 issue: pre row 2 ; pos row 1 ----
    pA2 = ld4(pp + 1024); pB2 = ld4(pp + 1280);
    qA1 = ld4(qq + 512);  qB1 = ld4(qq + 768);
    __builtin_amdgcn_sched_barrier(0);

    auto compute = [&](f32x4 pA, f32x4 pB, f32x4 qA, f32x4 qB, float* dst) {
        float sp = 0.f, sq = 0.f, d = 0.f;
        #pragma unroll
        for (int i = 0; i < 4; ++i) {
            sp = fmaf(pA[i], pA[i], sp); sp = fmaf(pB[i], pB[i], sp);
            sq = fmaf(qA[i], qA[i], sq); sq = fmaf(qB[i], qB[i], sq);
            d  = fmaf(pA[i], qA[i], d);  d  = fmaf(pB[i], qB[i], d);
        }
        #pragma unroll
        for (int m = 1; m < 64; m <<= 1) {
            sp += __shfl_xor(sp, m, 64);
            sq += __shfl_xor(sq, m, 64);
            d  += __shfl_xor(d,  m, 64);
        }
        const float np = fmaxf(sqrtf(sp), 1e-12f);
        const float nq = fmaxf(sqrtf(sq), 1e-12f);
        // 1 - sigmoid(x) = 1 / (1 + e^x)
        const float w  = 1.0f / (1.0f + __expf(d / (np * nq)));
        *reinterpret_cast<f32x4*>(dst)       = qA * w;
        *reinterpret_cast<f32x4*>(dst + 256) = qB * w;
    };

    // ---- compute row 0 (pre row 2 + pos row 1 stay in flight: vmcnt(4)) ----
    compute(pA0, pB0, qA0, qB0, oo);
    __builtin_amdgcn_sched_barrier(0);

    // ---- stage 2 issue: pre row 3 ; pos row 2 ----
    pA3 = ld4(pp + 1536); pB3 = ld4(pp + 1792);
    qA2 = ld4(qq + 1024); qB2 = ld4(qq + 1280);
    __builtin_amdgcn_sched_barrier(0);

    compute(pA1, pB1, qA1, qB1, oo + 512);
    __builtin_amdgcn_sched_barrier(0);

    // ---- stage 3 issue: pos row 3 ----
    qA3 = ld4(qq + 1536); qB3 = ld4(qq + 1792);
    __builtin_amdgcn_sched_barrier(0);

    compute(pA2, pB2, qA2, qB2, oo + 1024);
    __builtin_amdgcn_sched_barrier(0);

    compute(pA3, pB3, qA3, qB3, oo + 1536);
}

extern "C" void kernel_launch(void* const* d_in, const int* in_sizes, int n_in,
                              void* d_out, int out_size, void* d_ws, size_t ws_size,
                              hipStream_t stream) {
    const float* pre = (const float*)d_in[0];
    const float* pos = (const float*)d_in[1];
    float* out = (float*)d_out;

    // 4 rows/wave, 4 waves/block -> 16 rows per block
    const int blocks = ROWS / 16;   // 4096
    tokenmixer_kernel<<<blocks, 256, 0, stream>>>(pre, pos, out);
}